// Round 4
// baseline (504.085 us; speedup 1.0000x reference)
//
#include <hip/hip_runtime.h>
#include <hip/hip_bf16.h>

#define N_TOKENS 65536
#define MAXF 512
#define OUTF 1024
#define NGROUP 4

typedef __attribute__((ext_vector_type(8))) short short8;   // 8 bf16 (4 VGPRs)
typedef __attribute__((ext_vector_type(4))) float floatx4;
typedef unsigned short ushort_t;
typedef unsigned int uint_t;

__device__ __forceinline__ uint_t f2bf(float f) {
    uint_t u = __float_as_uint(f);
    u += 0x7fffu + ((u >> 16) & 1u);   // RNE
    return u >> 16;
}

// ws layout (bytes):
//   cnt:    0       (4 ints: per-group counts, atomic; zeroed via hipMemsetAsync)
//   lists:  16384   (4 * 65536 ints: per-group token id arrays, group g at g*65536)
//   xb:     2MiB    (K-PACKED bf16 rows, group-prefix packed)
//   wb:     2MiB+64MiB (K-PACKED bf16 weights, per-group starts {0,64,192,448}*1024)
#define OFF_CNT    0
#define OFF_LISTS  16384
#define OFF_XB     (2u<<20)
#define OFF_WB     ((2u<<20) + ((size_t)N_TOKENS*MAXF*2))
#define WS_FULL    (OFF_WB + (size_t)NGROUP*OUTF*MAXF*2)
#define WS_MIN     (OFF_LISTS + (size_t)NGROUP*N_TOKENS*4)

// ---------- fused hist+scan+scatter: per-group dense lists via atomics ----------
__global__ void prep_kernel(const int* __restrict__ sizes, int* __restrict__ cnt,
                            int* __restrict__ lists) {
    __shared__ int wcnt[4][NGROUP];
    __shared__ int gbase[NGROUP];
    int t = threadIdx.x, wave = t >> 6, lane = t & 63;
    int tok = blockIdx.x * 256 + t;
    int g = __ffs(sizes[tok]) - 7;     // 64->0,128->1,256->2,512->3
    int pos = 0;
    #pragma unroll
    for (int gg = 0; gg < NGROUP; ++gg) {
        unsigned long long m = __ballot(g == gg);
        if (g == gg) pos = __popcll(m & ((1ull << lane) - 1ull));
        if (lane == 0) wcnt[wave][gg] = __popcll(m);
    }
    __syncthreads();
    if (t < NGROUP) {
        int tot = wcnt[0][t] + wcnt[1][t] + wcnt[2][t] + wcnt[3][t];
        gbase[t] = atomicAdd(&cnt[t], tot);   // device-scope, disjoint ranges
    }
    __syncthreads();
    int off = gbase[g];
    for (int w = 0; w < wave; ++w) off += wcnt[w][g];
    lists[(g << 16) + off + pos] = tok;
}

// ---------- fused conversion: weights (ids < 122880) then x, K-PACKED ----------
__global__ void conv_kernel(const float* __restrict__ x, const float* __restrict__ weight,
                            const int* __restrict__ cnt, const int* __restrict__ lists,
                            ushort_t* __restrict__ xb, ushort_t* __restrict__ wb) {
    int c0 = cnt[0], c1 = cnt[1], c2 = cnt[2], c3 = cnt[3];
    int p1 = c0 << 3;
    int p2 = p1 + (c1 << 4);
    int p3 = p2 + (c2 << 5);
    int xT = p3 + (c3 << 6);
    int T = 122880 + xT;
    int xs1 = c0 << 6;
    int xs2 = xs1 + (c1 << 7);
    int xs3 = xs2 + (c2 << 8);
    int stride = gridDim.x * blockDim.x;
    for (int id = blockIdx.x * blockDim.x + threadIdx.x; id < T; id += stride) {
        const floatx4* src;
        ushort_t* dst;
        if (id < 122880) {
            int g, local, wsb;
            if (id < 8192)       { g = 0; local = id;         wsb = 0;      }
            else if (id < 24576) { g = 1; local = id - 8192;  wsb = 65536;  }
            else if (id < 57344) { g = 2; local = id - 24576; wsb = 196608; }
            else                 { g = 3; local = id - 57344; wsb = 458752; }
            int shift = 3 + g;
            int row = local >> shift;
            int k = (local - (row << shift)) << 3;
            src = (const floatx4*)(weight + (size_t)g * OUTF * MAXF + (size_t)row * MAXF + k);
            dst = wb + wsb + ((size_t)row << (6 + g)) + k;
        } else {
            int xid = id - 122880;
            int g, local, xs;
            if (xid < p1)      { g = 0; local = xid;      xs = 0;   }
            else if (xid < p2) { g = 1; local = xid - p1; xs = xs1; }
            else if (xid < p3) { g = 2; local = xid - p2; xs = xs2; }
            else               { g = 3; local = xid - p3; xs = xs3; }
            int shift = 3 + g;
            int sl = local >> shift;
            int k = (local - (sl << shift)) << 3;
            int tok = lists[(g << 16) + sl];
            src = (const floatx4*)(x + (size_t)tok * MAXF + k);
            dst = xb + (size_t)xs + ((size_t)sl << (6 + g)) + k;
        }
        floatx4 a = src[0], b = src[1];
        short8 v;
        v[0] = (short)f2bf(a[0]); v[1] = (short)f2bf(a[1]);
        v[2] = (short)f2bf(a[2]); v[3] = (short)f2bf(a[3]);
        v[4] = (short)f2bf(b[0]); v[5] = (short)f2bf(b[1]);
        v[6] = (short)f2bf(b[2]); v[7] = (short)f2bf(b[3]);
        *(short8*)dst = v;
    }
}

#define GLOAD_LDS16(gptr, lptr)                                                \
    __builtin_amdgcn_global_load_lds(                                          \
        (const __attribute__((address_space(1))) uint_t*)(gptr),               \
        (__attribute__((address_space(3))) uint_t*)(lptr), 16, 0, 0)

// ---------- bf16 grouped GEMM: 256x256 tile, 3-buffer depth-2 counted-vmcnt ----
// LDS (dynamic 99328 B): 3 x {As 16K | Bs 16K} + oidx 1K.
// XOR swizzle (16B granule): physical q = logical q ^ ((row>>1)&3), applied on
// BOTH the global_load_lds source offset and the fragment-read address (rule #21).
// Tile order: LONGEST-FIRST (g=3 -> g=0); bijective XCD swizzle (m204).
// COUNT HARDENING (R3 post-mortem): ALL non-staging vmem (oidx list read, bias
// loads) is issued pre-loop and drained by one vmcnt(0) BEFORE prologue staging.
// The K-loop is then vmem-pure: each wave's outstanding vmem = its own staging
// loads only, so vmcnt(4) exactly means "next buffer's 4 loads landed",
// independent of compiler scheduling.
__global__ __launch_bounds__(512, 1) void gemm_bf16_kernel(
    const ushort_t* __restrict__ xb, const ushort_t* __restrict__ wb,
    const float* __restrict__ bias, const int* __restrict__ cnt,
    const int* __restrict__ lists, float* __restrict__ out) {

    extern __shared__ char sh[];

    const int c0 = cnt[0], c1 = cnt[1], c2 = cnt[2], c3 = cnt[3];
    const int T3 = ((c3 + 255) >> 8) << 2;
    const int T2 = ((c2 + 255) >> 8) << 2;
    const int T1 = ((c1 + 255) >> 8) << 2;
    const int T0 = ((c0 + 255) >> 8) << 2;
    const int tcount = T3 + T2 + T1 + T0;
    const int xs1 = c0 << 6;
    const int xs2 = xs1 + (c1 << 7);
    const int xs3 = xs2 + (c2 << 8);

    int id = blockIdx.x;
    if (id >= tcount) return;

    // bijective XCD swizzle: XCD k gets a contiguous chunk of tile ids
    {
        int q = tcount >> 3, r = tcount & 7;
        int xcd = id & 7, idx = id >> 3;
        id = ((xcd < r) ? xcd * (q + 1) : r * (q + 1) + (xcd - r) * q) + idx;
    }

    // decode, longest group first (kills the g=3 tail)
    int g, local, count, xs, wsb;
    if (id < T3)                { g = 3; local = id;                count = c3; xs = xs3; wsb = 458752; }
    else if (id < T3 + T2)      { g = 2; local = id - T3;           count = c2; xs = xs2; wsb = 196608; }
    else if (id < T3 + T2 + T1) { g = 1; local = id - T3 - T2;      count = c1; xs = xs1; wsb = 65536;  }
    else                        { g = 0; local = id - T3 - T2 - T1; count = c0; xs = 0;   wsb = 0;      }

    const int mt = local >> 2, nt = local & 3;
    const int m_base = mt << 8;
    const int n_base = nt << 8;
    const int K_log = 6 + g;
    const int nsteps = 1 << (g + 1);           // K/32 (>= 2)
    const int rows = min(256, count - m_base);

    const int t = threadIdx.x;
    const int wave = t >> 6, lane = t & 63;
    const int wm = wave >> 2, wn = wave & 3;   // 2 x 4 wave grid
    const int quad = lane >> 4, l16 = lane & 15;
    const int rsub = lane >> 2;                            // row in 16-row chunk
    const int kq = (((lane & 3) ^ ((lane >> 3) & 3)) << 3); // swizzled src granule
    const int rp = (l16 >> 1) & 3;                          // read-side swizzle term

    int* oidx = (int*)(sh + 98304);

    // ---- pre-loop vmem: oidx list read (+LDS write) and bias loads ----
    if (t < 256) {
        int m = m_base + t;
        oidx[t] = (m < count) ? lists[(g << 16) + m] : 0;
    }
    float bvreg[4];
    #pragma unroll
    for (int ni = 0; ni < 4; ++ni)
        bvreg[ni] = bias[g * OUTF + n_base + wn * 64 + ni * 16 + l16];

    // staging source pointers (K-invariant; add k0 each step)
    const ushort_t* aptr[2];
    const ushort_t* bptr[2];
    #pragma unroll
    for (int j = 0; j < 2; ++j) {
        int br = wave * 32 + j * 16;
        int ar = min(m_base + br + rsub, count - 1);
        aptr[j] = xb + (size_t)xs + ((size_t)ar << K_log) + kq;
        bptr[j] = wb + (size_t)wsb + ((size_t)(n_base + br + rsub) << K_log) + kq;
    }

    floatx4 acc[8][4];
    #pragma unroll
    for (int i = 0; i < 8; ++i)
        #pragma unroll
        for (int j = 0; j < 4; ++j) acc[i][j] = (floatx4)(0.0f);

    // drain ALL pre-loop vmem so loop-counting is exact (codegen-independent)
    asm volatile("s_waitcnt vmcnt(0)" ::: "memory");

    // prologue: stage steps 0 and 1 (depth-2)
    #pragma unroll
    for (int j = 0; j < 2; ++j) {
        int br = wave * 32 + j * 16;
        GLOAD_LDS16(aptr[j], sh + br * 64);
        GLOAD_LDS16(bptr[j], sh + 16384 + br * 64);
    }
    #pragma unroll
    for (int j = 0; j < 2; ++j) {
        int br = wave * 32 + j * 16;
        GLOAD_LDS16(aptr[j] + 32, sh + 32768 + br * 64);
        GLOAD_LDS16(bptr[j] + 32, sh + 32768 + 16384 + br * 64);
    }

    int buf = 0;
    for (int s = 0; s < nsteps; ++s) {
        // counted wait: this step's 4 staging loads (oldest) must be done; the
        // next buffer's 4 may stay in flight. lgkmcnt(0) retires our ds_reads
        // of buffer (s-1) before the barrier, closing the WAR window for the
        // staging into that buffer issued after the barrier.
        if (s + 1 < nsteps)
            asm volatile("s_waitcnt vmcnt(4) lgkmcnt(0)" ::: "memory");
        else
            asm volatile("s_waitcnt vmcnt(0) lgkmcnt(0)" ::: "memory");
        __builtin_amdgcn_s_barrier();
        asm volatile("" ::: "memory");

        const ushort_t* Ab = (const ushort_t*)(sh + buf * 32768);
        const ushort_t* Bb = (const ushort_t*)(sh + buf * 32768 + 16384);
        short8 af[8], bfr[4];
        #pragma unroll
        for (int mi = 0; mi < 8; ++mi)
            af[mi] = *(const short8*)&Ab[(wm * 128 + mi * 16 + l16) * 32 + ((quad ^ rp) << 3)];
        #pragma unroll
        for (int ni = 0; ni < 4; ++ni)
            bfr[ni] = *(const short8*)&Bb[(wn * 64 + ni * 16 + l16) * 32 + ((quad ^ rp) << 3)];

        #pragma unroll
        for (int mi = 0; mi < 8; ++mi)
            #pragma unroll
            for (int ni = 0; ni < 4; ++ni)
                acc[mi][ni] = __builtin_amdgcn_mfma_f32_16x16x32_bf16(
                    af[mi], bfr[ni], acc[mi][ni], 0, 0, 0);

        // stage step s+2 into buffer (buf+2)%3 (its last readers were iter s-1;
        // their reads retired before the iter-s barrier via lgkmcnt(0))
        if (s + 2 < nsteps) {
            int k0 = (s + 2) << 5;
            int bn = buf + 2; if (bn >= 3) bn -= 3;
            char* dstA = sh + bn * 32768;
            #pragma unroll
            for (int j = 0; j < 2; ++j) {
                int br = wave * 32 + j * 16;
                GLOAD_LDS16(aptr[j] + k0, dstA + br * 64);
                GLOAD_LDS16(bptr[j] + k0, dstA + 16384 + br * 64);
            }
        }
        buf = (buf == 2) ? 0 : buf + 1;
    }

    // epilogue: store-only (bias in registers, oidx in LDS)
    #pragma unroll
    for (int ni = 0; ni < 4; ++ni) {
        int col = n_base + wn * 64 + ni * 16 + l16;
        #pragma unroll
        for (int mi = 0; mi < 8; ++mi) {
            int mloc = wm * 128 + mi * 16 + quad * 4;
            #pragma unroll
            for (int r = 0; r < 4; ++r) {
                int m = mloc + r;
                if (m < rows)
                    out[(size_t)oidx[m] * OUTF + col] = acc[mi][ni][r] + bvreg[ni];
            }
        }
    }
}

// ---------- fallback: fp32 gather GEMM (per-group lists) ----------
__global__ __launch_bounds__(256) void gemm_fp32_kernel(
    const float* __restrict__ x, const float* __restrict__ weight,
    const float* __restrict__ bias, const int* __restrict__ cnt,
    const int* __restrict__ lists, float* __restrict__ out) {

    const int g = blockIdx.z;
    const int count = cnt[g];
    const int m_base = blockIdx.y * 128;
    if (m_base >= count) return;
    const int n_base = blockIdx.x * 128;
    const int K = 64 << g;
    const int rows = min(128, count - m_base);

    __shared__ ushort_t As[128][40];
    __shared__ ushort_t Bs[128][40];
    __shared__ int idxs[128];

    const int t = threadIdx.x;
    if (t < 128) idxs[t] = (t < rows) ? lists[(g << 16) + m_base + t]
                                      : lists[(g << 16) + m_base];
    __syncthreads();

    const int wave = t >> 6, lane = t & 63;
    const int wm = wave >> 1, wn = wave & 1;
    const int quad = lane >> 4, l16 = lane & 15;

    floatx4 acc[4][4];
    #pragma unroll
    for (int i = 0; i < 4; ++i)
        #pragma unroll
        for (int j = 0; j < 4; ++j) acc[i][j] = (floatx4)(0.0f);

    const float* wg = weight + (size_t)g * OUTF * MAXF;

    for (int k0 = 0; k0 < K; k0 += 32) {
        #pragma unroll
        for (int rep = 0; rep < 4; ++rep) {
            int id = t + rep * 256;
            int row = id >> 3;
            int kqq = id & 7;
            floatx4 av = *(const floatx4*)(x + (size_t)idxs[row] * MAXF + k0 + kqq * 4);
            unsigned long long pa = (unsigned long long)f2bf(av[0]) |
                ((unsigned long long)f2bf(av[1]) << 16) |
                ((unsigned long long)f2bf(av[2]) << 32) |
                ((unsigned long long)f2bf(av[3]) << 48);
            *(unsigned long long*)&As[row][kqq * 4] = pa;
            floatx4 bvv = *(const floatx4*)(wg + (size_t)(n_base + row) * MAXF + k0 + kqq * 4);
            unsigned long long pb = (unsigned long long)f2bf(bvv[0]) |
                ((unsigned long long)f2bf(bvv[1]) << 16) |
                ((unsigned long long)f2bf(bvv[2]) << 32) |
                ((unsigned long long)f2bf(bvv[3]) << 48);
            *(unsigned long long*)&Bs[row][kqq * 4] = pb;
        }
        __syncthreads();

        short8 af[4], bfr[4];
        #pragma unroll
        for (int mi = 0; mi < 4; ++mi)
            af[mi] = *(const short8*)&As[wm * 64 + mi * 16 + l16][quad * 8];
        #pragma unroll
        for (int ni = 0; ni < 4; ++ni)
            bfr[ni] = *(const short8*)&Bs[wn * 64 + ni * 16 + l16][quad * 8];
        #pragma unroll
        for (int mi = 0; mi < 4; ++mi)
            #pragma unroll
            for (int ni = 0; ni < 4; ++ni)
                acc[mi][ni] = __builtin_amdgcn_mfma_f32_16x16x32_bf16(
                    af[mi], bfr[ni], acc[mi][ni], 0, 0, 0);
        __syncthreads();
    }

    #pragma unroll
    for (int ni = 0; ni < 4; ++ni) {
        int col = n_base + wn * 64 + ni * 16 + l16;
        float bv = bias[g * OUTF + col];
        #pragma unroll
        for (int mi = 0; mi < 4; ++mi) {
            int mloc = wm * 64 + mi * 16 + quad * 4;
            #pragma unroll
            for (int r = 0; r < 4; ++r) {
                int m = mloc + r;
                if (m < rows)
                    out[(size_t)idxs[m] * OUTF + col] = acc[mi][ni][r] + bv;
            }
        }
    }
}

extern "C" void kernel_launch(void* const* d_in, const int* in_sizes, int n_in,
                              void* d_out, int out_size, void* d_ws, size_t ws_size,
                              hipStream_t stream) {
    const float* x      = (const float*)d_in[0];
    const int*   sizes  = (const int*)d_in[1];
    const float* weight = (const float*)d_in[2];
    const float* bias   = (const float*)d_in[3];
    float* out = (float*)d_out;

    char* ws = (char*)d_ws;
    int* cnt   = (int*)(ws + OFF_CNT);
    int* lists = (int*)(ws + OFF_LISTS);
    ushort_t* xb = (ushort_t*)(ws + OFF_XB);
    ushort_t* wb = (ushort_t*)(ws + OFF_WB);

    hipMemsetAsync(ws + OFF_CNT, 0, NGROUP * sizeof(int), stream);
    prep_kernel<<<N_TOKENS / 256, 256, 0, stream>>>(sizes, cnt, lists);

    if (ws_size >= WS_FULL) {
        static int attr_done = 0;
        if (!attr_done) {
            hipFuncSetAttribute((const void*)gemm_bf16_kernel,
                                hipFuncAttributeMaxDynamicSharedMemorySize, 99328);
            attr_done = 1;
        }
        conv_kernel<<<2048, 256, 0, stream>>>(x, weight, cnt, lists, xb, wb);
        // flat tile grid upper bound: 4 * (ceil(65536/256) + 3) = 1036
        gemm_bf16_kernel<<<1036, 512, 99328, stream>>>(xb, wb, bias, cnt, lists, out);
    } else {
        dim3 grid(OUTF / 128, N_TOKENS / 128, NGROUP);
        gemm_fp32_kernel<<<grid, 256, 0, stream>>>(x, weight, bias, cnt, lists, out);
    }
}

// Round 5
// 415.067 us; speedup vs baseline: 1.2145x; 1.2145x over previous
//
#include <hip/hip_runtime.h>
#include <hip/hip_bf16.h>

#define N_TOKENS 65536
#define MAXF 512
#define OUTF 1024
#define NGROUP 4

typedef __attribute__((ext_vector_type(8))) short short8;   // 8 bf16 (4 VGPRs)
typedef __attribute__((ext_vector_type(4))) float floatx4;
typedef unsigned short ushort_t;
typedef unsigned int uint_t;

__device__ __forceinline__ uint_t f2bf(float f) {
    uint_t u = __float_as_uint(f);
    u += 0x7fffu + ((u >> 16) & 1u);   // RNE
    return u >> 16;
}

// ws layout (bytes):
//   cnt:    0       (4 ints: per-group counts, atomic; zeroed via hipMemsetAsync)
//   lists:  16384   (4 * 65536 ints: per-group token id arrays, group g at g*65536)
//   xb:     2MiB    (K-PACKED bf16 rows, group-prefix packed)
//   wb:     2MiB+64MiB (K-PACKED bf16 weights, per-group starts {0,64,192,448}*1024)
#define OFF_CNT    0
#define OFF_LISTS  16384
#define OFF_XB     (2u<<20)
#define OFF_WB     ((2u<<20) + ((size_t)N_TOKENS*MAXF*2))
#define WS_FULL    (OFF_WB + (size_t)NGROUP*OUTF*MAXF*2)
#define WS_MIN     (OFF_LISTS + (size_t)NGROUP*N_TOKENS*4)

// ---------- fused hist+scan+scatter: per-group dense lists via atomics ----------
__global__ void prep_kernel(const int* __restrict__ sizes, int* __restrict__ cnt,
                            int* __restrict__ lists) {
    __shared__ int wcnt[4][NGROUP];
    __shared__ int gbase[NGROUP];
    int t = threadIdx.x, wave = t >> 6, lane = t & 63;
    int tok = blockIdx.x * 256 + t;
    int g = __ffs(sizes[tok]) - 7;     // 64->0,128->1,256->2,512->3
    int pos = 0;
    #pragma unroll
    for (int gg = 0; gg < NGROUP; ++gg) {
        unsigned long long m = __ballot(g == gg);
        if (g == gg) pos = __popcll(m & ((1ull << lane) - 1ull));
        if (lane == 0) wcnt[wave][gg] = __popcll(m);
    }
    __syncthreads();
    if (t < NGROUP) {
        int tot = wcnt[0][t] + wcnt[1][t] + wcnt[2][t] + wcnt[3][t];
        gbase[t] = atomicAdd(&cnt[t], tot);   // device-scope, disjoint ranges
    }
    __syncthreads();
    int off = gbase[g];
    for (int w = 0; w < wave; ++w) off += wcnt[w][g];
    lists[(g << 16) + off + pos] = tok;
}

// ---------- fused conversion: weights (ids < 122880) then x, K-PACKED ----------
__global__ void conv_kernel(const float* __restrict__ x, const float* __restrict__ weight,
                            const int* __restrict__ cnt, const int* __restrict__ lists,
                            ushort_t* __restrict__ xb, ushort_t* __restrict__ wb) {
    int c0 = cnt[0], c1 = cnt[1], c2 = cnt[2], c3 = cnt[3];
    int p1 = c0 << 3;
    int p2 = p1 + (c1 << 4);
    int p3 = p2 + (c2 << 5);
    int xT = p3 + (c3 << 6);
    int T = 122880 + xT;
    int xs1 = c0 << 6;
    int xs2 = xs1 + (c1 << 7);
    int xs3 = xs2 + (c2 << 8);
    int stride = gridDim.x * blockDim.x;
    for (int id = blockIdx.x * blockDim.x + threadIdx.x; id < T; id += stride) {
        const floatx4* src;
        ushort_t* dst;
        if (id < 122880) {
            int g, local, wsb;
            if (id < 8192)       { g = 0; local = id;         wsb = 0;      }
            else if (id < 24576) { g = 1; local = id - 8192;  wsb = 65536;  }
            else if (id < 57344) { g = 2; local = id - 24576; wsb = 196608; }
            else                 { g = 3; local = id - 57344; wsb = 458752; }
            int shift = 3 + g;
            int row = local >> shift;
            int k = (local - (row << shift)) << 3;
            src = (const floatx4*)(weight + (size_t)g * OUTF * MAXF + (size_t)row * MAXF + k);
            dst = wb + wsb + ((size_t)row << (6 + g)) + k;
        } else {
            int xid = id - 122880;
            int g, local, xs;
            if (xid < p1)      { g = 0; local = xid;      xs = 0;   }
            else if (xid < p2) { g = 1; local = xid - p1; xs = xs1; }
            else if (xid < p3) { g = 2; local = xid - p2; xs = xs2; }
            else               { g = 3; local = xid - p3; xs = xs3; }
            int shift = 3 + g;
            int sl = local >> shift;
            int k = (local - (sl << shift)) << 3;
            int tok = lists[(g << 16) + sl];
            src = (const floatx4*)(x + (size_t)tok * MAXF + k);
            dst = xb + (size_t)xs + ((size_t)sl << (6 + g)) + k;
        }
        floatx4 a = src[0], b = src[1];
        short8 v;
        v[0] = (short)f2bf(a[0]); v[1] = (short)f2bf(a[1]);
        v[2] = (short)f2bf(a[2]); v[3] = (short)f2bf(a[3]);
        v[4] = (short)f2bf(b[0]); v[5] = (short)f2bf(b[1]);
        v[6] = (short)f2bf(b[2]); v[7] = (short)f2bf(b[3]);
        *(short8*)dst = v;
    }
}

#define GLOAD_LDS16(gptr, lptr)                                                \
    __builtin_amdgcn_global_load_lds(                                          \
        (const __attribute__((address_space(1))) uint_t*)(gptr),               \
        (__attribute__((address_space(3))) uint_t*)(lptr), 16, 0, 0)

// ---------- bf16 grouped GEMM: 256x256 tile, 3-buffer depth-2 counted-vmcnt ----
// K-loop identical to R4 (verified passing). NEW: LDS-transpose epilogue —
// 4 chunks of 64 rows deposited into [64][260]-float LDS, then float4
// nontemporal stores: each wave writes a full 1KB contiguous row slice
// (8 full 128B lines per instr) instead of scattered 64B segments.
__global__ __launch_bounds__(512, 1) void gemm_bf16_kernel(
    const ushort_t* __restrict__ xb, const ushort_t* __restrict__ wb,
    const float* __restrict__ bias, const int* __restrict__ cnt,
    const int* __restrict__ lists, float* __restrict__ out) {

    extern __shared__ char sh[];

    const int c0 = cnt[0], c1 = cnt[1], c2 = cnt[2], c3 = cnt[3];
    const int T3 = ((c3 + 255) >> 8) << 2;
    const int T2 = ((c2 + 255) >> 8) << 2;
    const int T1 = ((c1 + 255) >> 8) << 2;
    const int T0 = ((c0 + 255) >> 8) << 2;
    const int tcount = T3 + T2 + T1 + T0;
    const int xs1 = c0 << 6;
    const int xs2 = xs1 + (c1 << 7);
    const int xs3 = xs2 + (c2 << 8);

    int id = blockIdx.x;
    if (id >= tcount) return;

    // bijective XCD swizzle: XCD k gets a contiguous chunk of tile ids
    {
        int q = tcount >> 3, r = tcount & 7;
        int xcd = id & 7, idx = id >> 3;
        id = ((xcd < r) ? xcd * (q + 1) : r * (q + 1) + (xcd - r) * q) + idx;
    }

    // decode, longest group first (kills the g=3 tail)
    int g, local, count, xs, wsb;
    if (id < T3)                { g = 3; local = id;                count = c3; xs = xs3; wsb = 458752; }
    else if (id < T3 + T2)      { g = 2; local = id - T3;           count = c2; xs = xs2; wsb = 196608; }
    else if (id < T3 + T2 + T1) { g = 1; local = id - T3 - T2;      count = c1; xs = xs1; wsb = 65536;  }
    else                        { g = 0; local = id - T3 - T2 - T1; count = c0; xs = 0;   wsb = 0;      }

    const int mt = local >> 2, nt = local & 3;
    const int m_base = mt << 8;
    const int n_base = nt << 8;
    const int K_log = 6 + g;
    const int nsteps = 1 << (g + 1);           // K/32 (>= 2)
    const int rows = min(256, count - m_base);

    const int t = threadIdx.x;
    const int wave = t >> 6, lane = t & 63;
    const int wm = wave >> 2, wn = wave & 3;   // 2 x 4 wave grid
    const int quad = lane >> 4, l16 = lane & 15;
    const int rsub = lane >> 2;                            // row in 16-row chunk
    const int kq = (((lane & 3) ^ ((lane >> 3) & 3)) << 3); // swizzled src granule
    const int rp = (l16 >> 1) & 3;                          // read-side swizzle term

    int* oidx = (int*)(sh + 98304);

    // ---- pre-loop vmem: oidx list read (+LDS write) and bias loads ----
    if (t < 256) {
        int m = m_base + t;
        oidx[t] = (m < count) ? lists[(g << 16) + m] : 0;
    }
    float bvreg[4];
    #pragma unroll
    for (int ni = 0; ni < 4; ++ni)
        bvreg[ni] = bias[g * OUTF + n_base + wn * 64 + ni * 16 + l16];

    // staging source pointers (K-invariant; add k0 each step)
    const ushort_t* aptr[2];
    const ushort_t* bptr[2];
    #pragma unroll
    for (int j = 0; j < 2; ++j) {
        int br = wave * 32 + j * 16;
        int ar = min(m_base + br + rsub, count - 1);
        aptr[j] = xb + (size_t)xs + ((size_t)ar << K_log) + kq;
        bptr[j] = wb + (size_t)wsb + ((size_t)(n_base + br + rsub) << K_log) + kq;
    }

    floatx4 acc[8][4];
    #pragma unroll
    for (int i = 0; i < 8; ++i)
        #pragma unroll
        for (int j = 0; j < 4; ++j) acc[i][j] = (floatx4)(0.0f);

    // drain ALL pre-loop vmem so loop-counting is exact (codegen-independent)
    asm volatile("s_waitcnt vmcnt(0)" ::: "memory");

    // prologue: stage steps 0 and 1 (depth-2)
    #pragma unroll
    for (int j = 0; j < 2; ++j) {
        int br = wave * 32 + j * 16;
        GLOAD_LDS16(aptr[j], sh + br * 64);
        GLOAD_LDS16(bptr[j], sh + 16384 + br * 64);
    }
    #pragma unroll
    for (int j = 0; j < 2; ++j) {
        int br = wave * 32 + j * 16;
        GLOAD_LDS16(aptr[j] + 32, sh + 32768 + br * 64);
        GLOAD_LDS16(bptr[j] + 32, sh + 32768 + 16384 + br * 64);
    }

    int buf = 0;
    for (int s = 0; s < nsteps; ++s) {
        // counted wait: this step's 4 staging loads (oldest) must be done; the
        // next buffer's 4 may stay in flight. lgkmcnt(0) retires our ds_reads
        // of buffer (s-1) before the barrier, closing the WAR window for the
        // staging into that buffer issued after the barrier.
        if (s + 1 < nsteps)
            asm volatile("s_waitcnt vmcnt(4) lgkmcnt(0)" ::: "memory");
        else
            asm volatile("s_waitcnt vmcnt(0) lgkmcnt(0)" ::: "memory");
        __builtin_amdgcn_s_barrier();
        asm volatile("" ::: "memory");

        const ushort_t* Ab = (const ushort_t*)(sh + buf * 32768);
        const ushort_t* Bb = (const ushort_t*)(sh + buf * 32768 + 16384);
        short8 af[8], bfr[4];
        #pragma unroll
        for (int mi = 0; mi < 8; ++mi)
            af[mi] = *(const short8*)&Ab[(wm * 128 + mi * 16 + l16) * 32 + ((quad ^ rp) << 3)];
        #pragma unroll
        for (int ni = 0; ni < 4; ++ni)
            bfr[ni] = *(const short8*)&Bb[(wn * 64 + ni * 16 + l16) * 32 + ((quad ^ rp) << 3)];

        #pragma unroll
        for (int mi = 0; mi < 8; ++mi)
            #pragma unroll
            for (int ni = 0; ni < 4; ++ni)
                acc[mi][ni] = __builtin_amdgcn_mfma_f32_16x16x32_bf16(
                    af[mi], bfr[ni], acc[mi][ni], 0, 0, 0);

        // stage step s+2 into buffer (buf+2)%3 (its last readers were iter s-1;
        // their reads retired before the iter-s barrier via lgkmcnt(0))
        if (s + 2 < nsteps) {
            int k0 = (s + 2) << 5;
            int bn = buf + 2; if (bn >= 3) bn -= 3;
            char* dstA = sh + bn * 32768;
            #pragma unroll
            for (int j = 0; j < 2; ++j) {
                int br = wave * 32 + j * 16;
                GLOAD_LDS16(aptr[j] + k0, dstA + br * 64);
                GLOAD_LDS16(bptr[j] + k0, dstA + 16384 + br * 64);
            }
        }
        buf = (buf == 2) ? 0 : buf + 1;
    }

    __syncthreads();   // all staging vmem drained (final-iter vmcnt(0)); LDS free

    // ---- LDS-transpose epilogue: 4 chunks of 64 rows, stride 260 floats ----
    // Deposit: wave (wm,wn) owns rows wm*128+mi*16+quad*4+r, cols wn*64+ni*16+l16.
    // Chunk c covers rows [64c, 64c+64): wm == c>>1, mi in [(c&1)*4, (c&1)*4+4).
    // Bank check (stride 260): quad adds 1040 floats %32 = 16 -> 2-way (free).
    float* shf = (float*)sh;
    #pragma unroll
    for (int c = 0; c < 4; ++c) {
        if (wm == (c >> 1)) {
            int mi0 = (c & 1) * 4;
            #pragma unroll
            for (int mm = 0; mm < 4; ++mm) {
                #pragma unroll
                for (int ni = 0; ni < 4; ++ni) {
                    int col = wn * 64 + ni * 16 + l16;
                    #pragma unroll
                    for (int r = 0; r < 4; ++r) {
                        int lrow = mm * 16 + quad * 4 + r;
                        shf[lrow * 260 + col] = acc[mi0 + mm][ni][r] + bvreg[ni];
                    }
                }
            }
        }
        __syncthreads();
        // write: 64 rows x 256 floats = 4096 float4; each thread 8. Consecutive
        // lanes cover one full row (64 f4 = 1KB contiguous -> 8 full HBM lines).
        #pragma unroll
        for (int k = 0; k < 8; ++k) {
            int idx = t + k * 512;
            int row = idx >> 6;
            int f4  = idx & 63;
            int m = c * 64 + row;
            if (m < rows) {
                floatx4 v = *(const floatx4*)&shf[row * 260 + f4 * 4];
                __builtin_nontemporal_store(
                    v, (floatx4*)&out[(size_t)oidx[m] * OUTF + n_base + f4 * 4]);
            }
        }
        __syncthreads();
    }
}

// ---------- fallback: fp32 gather GEMM (per-group lists) ----------
__global__ __launch_bounds__(256) void gemm_fp32_kernel(
    const float* __restrict__ x, const float* __restrict__ weight,
    const float* __restrict__ bias, const int* __restrict__ cnt,
    const int* __restrict__ lists, float* __restrict__ out) {

    const int g = blockIdx.z;
    const int count = cnt[g];
    const int m_base = blockIdx.y * 128;
    if (m_base >= count) return;
    const int n_base = blockIdx.x * 128;
    const int K = 64 << g;
    const int rows = min(128, count - m_base);

    __shared__ ushort_t As[128][40];
    __shared__ ushort_t Bs[128][40];
    __shared__ int idxs[128];

    const int t = threadIdx.x;
    if (t < 128) idxs[t] = (t < rows) ? lists[(g << 16) + m_base + t]
                                      : lists[(g << 16) + m_base];
    __syncthreads();

    const int wave = t >> 6, lane = t & 63;
    const int wm = wave >> 1, wn = wave & 1;
    const int quad = lane >> 4, l16 = lane & 15;

    floatx4 acc[4][4];
    #pragma unroll
    for (int i = 0; i < 4; ++i)
        #pragma unroll
        for (int j = 0; j < 4; ++j) acc[i][j] = (floatx4)(0.0f);

    const float* wg = weight + (size_t)g * OUTF * MAXF;

    for (int k0 = 0; k0 < K; k0 += 32) {
        #pragma unroll
        for (int rep = 0; rep < 4; ++rep) {
            int id = t + rep * 256;
            int row = id >> 3;
            int kqq = id & 7;
            floatx4 av = *(const floatx4*)(x + (size_t)idxs[row] * MAXF + k0 + kqq * 4);
            unsigned long long pa = (unsigned long long)f2bf(av[0]) |
                ((unsigned long long)f2bf(av[1]) << 16) |
                ((unsigned long long)f2bf(av[2]) << 32) |
                ((unsigned long long)f2bf(av[3]) << 48);
            *(unsigned long long*)&As[row][kqq * 4] = pa;
            floatx4 bvv = *(const floatx4*)(wg + (size_t)(n_base + row) * MAXF + k0 + kqq * 4);
            unsigned long long pb = (unsigned long long)f2bf(bvv[0]) |
                ((unsigned long long)f2bf(bvv[1]) << 16) |
                ((unsigned long long)f2bf(bvv[2]) << 32) |
                ((unsigned long long)f2bf(bvv[3]) << 48);
            *(unsigned long long*)&Bs[row][kqq * 4] = pb;
        }
        __syncthreads();

        short8 af[4], bfr[4];
        #pragma unroll
        for (int mi = 0; mi < 4; ++mi)
            af[mi] = *(const short8*)&As[wm * 64 + mi * 16 + l16][quad * 8];
        #pragma unroll
        for (int ni = 0; ni < 4; ++ni)
            bfr[ni] = *(const short8*)&Bs[wn * 64 + ni * 16 + l16][quad * 8];
        #pragma unroll
        for (int mi = 0; mi < 4; ++mi)
            #pragma unroll
            for (int ni = 0; ni < 4; ++ni)
                acc[mi][ni] = __builtin_amdgcn_mfma_f32_16x16x32_bf16(
                    af[mi], bfr[ni], acc[mi][ni], 0, 0, 0);
        __syncthreads();
    }

    #pragma unroll
    for (int ni = 0; ni < 4; ++ni) {
        int col = n_base + wn * 64 + ni * 16 + l16;
        float bv = bias[g * OUTF + col];
        #pragma unroll
        for (int mi = 0; mi < 4; ++mi) {
            int mloc = wm * 64 + mi * 16 + quad * 4;
            #pragma unroll
            for (int r = 0; r < 4; ++r) {
                int m = mloc + r;
                if (m < rows)
                    out[(size_t)idxs[m] * OUTF + col] = acc[mi][ni][r] + bv;
            }
        }
    }
}

extern "C" void kernel_launch(void* const* d_in, const int* in_sizes, int n_in,
                              void* d_out, int out_size, void* d_ws, size_t ws_size,
                              hipStream_t stream) {
    const float* x      = (const float*)d_in[0];
    const int*   sizes  = (const int*)d_in[1];
    const float* weight = (const float*)d_in[2];
    const float* bias   = (const float*)d_in[3];
    float* out = (float*)d_out;

    char* ws = (char*)d_ws;
    int* cnt   = (int*)(ws + OFF_CNT);
    int* lists = (int*)(ws + OFF_LISTS);
    ushort_t* xb = (ushort_t*)(ws + OFF_XB);
    ushort_t* wb = (ushort_t*)(ws + OFF_WB);

    hipMemsetAsync(ws + OFF_CNT, 0, NGROUP * sizeof(int), stream);
    prep_kernel<<<N_TOKENS / 256, 256, 0, stream>>>(sizes, cnt, lists);

    if (ws_size >= WS_FULL) {
        static int attr_done = 0;
        if (!attr_done) {
            hipFuncSetAttribute((const void*)gemm_bf16_kernel,
                                hipFuncAttributeMaxDynamicSharedMemorySize, 99328);
            attr_done = 1;
        }
        conv_kernel<<<2048, 256, 0, stream>>>(x, weight, cnt, lists, xb, wb);
        // flat tile grid upper bound: 4 * (ceil(65536/256) + 3) = 1036
        gemm_bf16_kernel<<<1036, 512, 99328, stream>>>(xb, wb, bias, cnt, lists, out);
    } else {
        dim3 grid(OUTF / 128, N_TOKENS / 128, NGROUP);
        gemm_fp32_kernel<<<grid, 256, 0, stream>>>(x, weight, bias, cnt, lists, out);
    }
}

// Round 6
// 408.661 us; speedup vs baseline: 1.2335x; 1.0157x over previous
//
#include <hip/hip_runtime.h>
#include <hip/hip_bf16.h>

#define N_TOKENS 65536
#define MAXF 512
#define OUTF 1024
#define NGROUP 4

typedef __attribute__((ext_vector_type(8))) short short8;   // 8 bf16 (4 VGPRs)
typedef __attribute__((ext_vector_type(4))) float floatx4;
typedef unsigned short ushort_t;
typedef unsigned int uint_t;

__device__ __forceinline__ uint_t f2bf(float f) {
    uint_t u = __float_as_uint(f);
    u += 0x7fffu + ((u >> 16) & 1u);   // RNE
    return u >> 16;
}

// ws layout (bytes):
//   cnt:    0       (4 ints: per-group counts, atomic; zeroed via hipMemsetAsync)
//   lists:  16384   (4 * 65536 ints: per-group token id arrays, group g at g*65536)
//   xb:     2MiB    (K-PACKED bf16 rows, group-prefix packed)
//   wb:     2MiB+64MiB (K-PACKED bf16 weights, per-group starts {0,64,192,448}*1024)
#define OFF_CNT    0
#define OFF_LISTS  16384
#define OFF_XB     (2u<<20)
#define OFF_WB     ((2u<<20) + ((size_t)N_TOKENS*MAXF*2))
#define WS_FULL    (OFF_WB + (size_t)NGROUP*OUTF*MAXF*2)
#define WS_MIN     (OFF_LISTS + (size_t)NGROUP*N_TOKENS*4)

// ---------- fused hist+scan+scatter: per-group dense lists via atomics ----------
__global__ void prep_kernel(const int* __restrict__ sizes, int* __restrict__ cnt,
                            int* __restrict__ lists) {
    __shared__ int wcnt[4][NGROUP];
    __shared__ int gbase[NGROUP];
    int t = threadIdx.x, wave = t >> 6, lane = t & 63;
    int tok = blockIdx.x * 256 + t;
    int g = __ffs(sizes[tok]) - 7;     // 64->0,128->1,256->2,512->3
    int pos = 0;
    #pragma unroll
    for (int gg = 0; gg < NGROUP; ++gg) {
        unsigned long long m = __ballot(g == gg);
        if (g == gg) pos = __popcll(m & ((1ull << lane) - 1ull));
        if (lane == 0) wcnt[wave][gg] = __popcll(m);
    }
    __syncthreads();
    if (t < NGROUP) {
        int tot = wcnt[0][t] + wcnt[1][t] + wcnt[2][t] + wcnt[3][t];
        gbase[t] = atomicAdd(&cnt[t], tot);   // device-scope, disjoint ranges
    }
    __syncthreads();
    int off = gbase[g];
    for (int w = 0; w < wave; ++w) off += wcnt[w][g];
    lists[(g << 16) + off + pos] = tok;
}

// ---------- fused conversion: weights (ids < 122880) then x, K-PACKED ----------
__global__ void conv_kernel(const float* __restrict__ x, const float* __restrict__ weight,
                            const int* __restrict__ cnt, const int* __restrict__ lists,
                            ushort_t* __restrict__ xb, ushort_t* __restrict__ wb) {
    int c0 = cnt[0], c1 = cnt[1], c2 = cnt[2], c3 = cnt[3];
    int p1 = c0 << 3;
    int p2 = p1 + (c1 << 4);
    int p3 = p2 + (c2 << 5);
    int xT = p3 + (c3 << 6);
    int T = 122880 + xT;
    int xs1 = c0 << 6;
    int xs2 = xs1 + (c1 << 7);
    int xs3 = xs2 + (c2 << 8);
    int stride = gridDim.x * blockDim.x;
    for (int id = blockIdx.x * blockDim.x + threadIdx.x; id < T; id += stride) {
        const floatx4* src;
        ushort_t* dst;
        if (id < 122880) {
            int g, local, wsb;
            if (id < 8192)       { g = 0; local = id;         wsb = 0;      }
            else if (id < 24576) { g = 1; local = id - 8192;  wsb = 65536;  }
            else if (id < 57344) { g = 2; local = id - 24576; wsb = 196608; }
            else                 { g = 3; local = id - 57344; wsb = 458752; }
            int shift = 3 + g;
            int row = local >> shift;
            int k = (local - (row << shift)) << 3;
            src = (const floatx4*)(weight + (size_t)g * OUTF * MAXF + (size_t)row * MAXF + k);
            dst = wb + wsb + ((size_t)row << (6 + g)) + k;
        } else {
            int xid = id - 122880;
            int g, local, xs;
            if (xid < p1)      { g = 0; local = xid;      xs = 0;   }
            else if (xid < p2) { g = 1; local = xid - p1; xs = xs1; }
            else if (xid < p3) { g = 2; local = xid - p2; xs = xs2; }
            else               { g = 3; local = xid - p3; xs = xs3; }
            int shift = 3 + g;
            int sl = local >> shift;
            int k = (local - (sl << shift)) << 3;
            int tok = lists[(g << 16) + sl];
            src = (const floatx4*)(x + (size_t)tok * MAXF + k);
            dst = xb + (size_t)xs + ((size_t)sl << (6 + g)) + k;
        }
        floatx4 a = src[0], b = src[1];
        short8 v;
        v[0] = (short)f2bf(a[0]); v[1] = (short)f2bf(a[1]);
        v[2] = (short)f2bf(a[2]); v[3] = (short)f2bf(a[3]);
        v[4] = (short)f2bf(b[0]); v[5] = (short)f2bf(b[1]);
        v[6] = (short)f2bf(b[2]); v[7] = (short)f2bf(b[3]);
        *(short8*)dst = v;
    }
}

#define GLOAD_LDS16(gptr, lptr)                                                \
    __builtin_amdgcn_global_load_lds(                                          \
        (const __attribute__((address_space(1))) uint_t*)(gptr),               \
        (__attribute__((address_space(3))) uint_t*)(lptr), 16, 0, 0)

// ---------- bf16 grouped GEMM: 256x128 tile, 8 waves (4Mx2N), 2 blocks/CU -----
// Per-wave output 64x64 -> acc = 64 regs; __launch_bounds__(512,4) caps at 128
// regs -> 16 waves/CU. LDS 50176 B static (2buf x 24KB + oidx 1KB) -> 2
// blocks/CU by LDS too. Sync is plain __syncthreads() (2-phase, stage-early):
// codegen-proof; drains are hidden by the co-resident block (m114 overlap).
// Epilogue: LDS-transpose [64][132] chunks + float4 nontemporal row stores.
__global__ __launch_bounds__(512, 4) void gemm_bf16_kernel(
    const ushort_t* __restrict__ xb, const ushort_t* __restrict__ wb,
    const float* __restrict__ bias, const int* __restrict__ cnt,
    const int* __restrict__ lists, float* __restrict__ out) {

    __shared__ __align__(16) char sh[50176];   // 2x24KB staging + 1KB oidx

    const int c0 = cnt[0], c1 = cnt[1], c2 = cnt[2], c3 = cnt[3];
    // tiles per group: ceil(c/256) m-tiles x 8 n-tiles
    const int T3 = ((c3 + 255) >> 8) << 3;
    const int T2 = ((c2 + 255) >> 8) << 3;
    const int T1 = ((c1 + 255) >> 8) << 3;
    const int T0 = ((c0 + 255) >> 8) << 3;
    const int tcount = T3 + T2 + T1 + T0;
    const int xs1 = c0 << 6;
    const int xs2 = xs1 + (c1 << 7);
    const int xs3 = xs2 + (c2 << 8);

    int id = blockIdx.x;
    if (id >= tcount) return;

    // bijective XCD swizzle: XCD k gets a contiguous chunk of tile ids
    {
        int q = tcount >> 3, r = tcount & 7;
        int xcd = id & 7, idx = id >> 3;
        id = ((xcd < r) ? xcd * (q + 1) : r * (q + 1) + (xcd - r) * q) + idx;
    }

    // decode, longest group first (kills the tail)
    int g, local, count, xs, wsb;
    if (id < T3)                { g = 3; local = id;                count = c3; xs = xs3; wsb = 458752; }
    else if (id < T3 + T2)      { g = 2; local = id - T3;           count = c2; xs = xs2; wsb = 196608; }
    else if (id < T3 + T2 + T1) { g = 1; local = id - T3 - T2;      count = c1; xs = xs1; wsb = 65536;  }
    else                        { g = 0; local = id - T3 - T2 - T1; count = c0; xs = 0;   wsb = 0;      }

    const int mt = local >> 3, nt = local & 7;
    const int m_base = mt << 8;                // 256 rows
    const int n_base = nt << 7;                // 128 cols
    const int K_log = 6 + g;
    const int nsteps = 1 << (g + 1);           // K/32 (>= 2)
    const int rows = min(256, count - m_base);

    const int t = threadIdx.x;
    const int wave = t >> 6, lane = t & 63;
    const int wm = wave >> 1, wn = wave & 1;   // 4M x 2N wave grid
    const int quad = lane >> 4, l16 = lane & 15;
    const int rsub = lane >> 2;                // row within 16-row staging pass
    const int kq = (lane & 3) * 8;             // 16B granule within 32-elem row

    int* oidx = (int*)(sh + 49152);

    // ---- pre-loop: epilogue token ids -> LDS; bias -> regs ----
    if (t < 256) {
        int m = m_base + t;
        oidx[t] = (m < count) ? lists[(g << 16) + m] : 0;
    }
    float bvreg[4];
    #pragma unroll
    for (int ni = 0; ni < 4; ++ni)
        bvreg[ni] = bias[g * OUTF + n_base + wn * 64 + ni * 16 + l16];

    // staging source pointers (K-invariant; add k0 elems each step)
    const ushort_t* a0;
    const ushort_t* a1;
    const ushort_t* b0;
    {
        int r0 = min(m_base + wave * 32 + rsub, count - 1);
        int r1 = min(m_base + wave * 32 + 16 + rsub, count - 1);
        a0 = xb + (size_t)xs + ((size_t)r0 << K_log) + kq;
        a1 = xb + (size_t)xs + ((size_t)r1 << K_log) + kq;
        int br = n_base + wave * 16 + rsub;
        b0 = wb + (size_t)wsb + ((size_t)br << K_log) + kq;
    }

    floatx4 acc[4][4];
    #pragma unroll
    for (int i = 0; i < 4; ++i)
        #pragma unroll
        for (int j = 0; j < 4; ++j) acc[i][j] = (floatx4)(0.0f);

    // prologue: stage step 0 into buf 0 (3 gloads/thread: 2 A-passes + 1 B)
    GLOAD_LDS16(a0, sh + (wave * 32) * 64);
    GLOAD_LDS16(a1, sh + (wave * 32 + 16) * 64);
    GLOAD_LDS16(b0, sh + 16384 + wave * 16 * 64);
    __syncthreads();

    int buf = 0;
    for (int s = 0; s < nsteps; ++s) {
        // issue next step's staging EARLY (overlaps with frags+MFMA below)
        if (s + 1 < nsteps) {
            int k0 = (s + 1) << 5;
            char* d = sh + (buf ^ 1) * 24576;
            GLOAD_LDS16(a0 + k0, d + (wave * 32) * 64);
            GLOAD_LDS16(a1 + k0, d + (wave * 32 + 16) * 64);
            GLOAD_LDS16(b0 + k0, d + 16384 + wave * 16 * 64);
        }

        const ushort_t* Ab = (const ushort_t*)(sh + buf * 24576);
        const ushort_t* Bb = (const ushort_t*)(sh + buf * 24576 + 16384);
        short8 af[4], bfr[4];
        #pragma unroll
        for (int mi = 0; mi < 4; ++mi)
            af[mi] = *(const short8*)&Ab[(wm * 64 + mi * 16 + l16) * 32 + quad * 8];
        #pragma unroll
        for (int ni = 0; ni < 4; ++ni)
            bfr[ni] = *(const short8*)&Bb[(wn * 64 + ni * 16 + l16) * 32 + quad * 8];

        #pragma unroll
        for (int mi = 0; mi < 4; ++mi)
            #pragma unroll
            for (int ni = 0; ni < 4; ++ni)
                acc[mi][ni] = __builtin_amdgcn_mfma_f32_16x16x32_bf16(
                    af[mi], bfr[ni], acc[mi][ni], 0, 0, 0);

        __syncthreads();   // drains vmcnt+lgkm, barrier (compiler-managed, safe)
        buf ^= 1;
    }

    // ---- LDS-transpose epilogue: 4 chunks of 64 rows, [64][132] floats ----
    // Deposit banks: quad step = 528B -> 2-way (free). Store reads: stride-16B
    // row segments (conflict-free); each row = 512B contiguous (4 full lines).
    float* shf = (float*)sh;
    #pragma unroll
    for (int c = 0; c < 4; ++c) {
        if (wm == c) {
            #pragma unroll
            for (int mi = 0; mi < 4; ++mi) {
                #pragma unroll
                for (int ni = 0; ni < 4; ++ni) {
                    int col = wn * 64 + ni * 16 + l16;
                    #pragma unroll
                    for (int r = 0; r < 4; ++r) {
                        int lrow = mi * 16 + quad * 4 + r;
                        shf[lrow * 132 + col] = acc[mi][ni][r] + bvreg[ni];
                    }
                }
            }
        }
        __syncthreads();
        // 64 rows x 32 float4 = 2048 f4; 4 per thread. Consecutive 32 lanes
        // cover one full 512B row slice.
        #pragma unroll
        for (int k = 0; k < 4; ++k) {
            int idx = t + k * 512;
            int row = idx >> 5;
            int f4  = idx & 31;
            int m = c * 64 + row;
            if (m < rows) {
                floatx4 v = *(const floatx4*)&shf[row * 132 + f4 * 4];
                __builtin_nontemporal_store(
                    v, (floatx4*)&out[(size_t)oidx[m] * OUTF + n_base + f4 * 4]);
            }
        }
        __syncthreads();
    }
}

// ---------- fallback: fp32 gather GEMM (per-group lists) ----------
__global__ __launch_bounds__(256) void gemm_fp32_kernel(
    const float* __restrict__ x, const float* __restrict__ weight,
    const float* __restrict__ bias, const int* __restrict__ cnt,
    const int* __restrict__ lists, float* __restrict__ out) {

    const int g = blockIdx.z;
    const int count = cnt[g];
    const int m_base = blockIdx.y * 128;
    if (m_base >= count) return;
    const int n_base = blockIdx.x * 128;
    const int K = 64 << g;
    const int rows = min(128, count - m_base);

    __shared__ ushort_t As[128][40];
    __shared__ ushort_t Bs[128][40];
    __shared__ int idxs[128];

    const int t = threadIdx.x;
    if (t < 128) idxs[t] = (t < rows) ? lists[(g << 16) + m_base + t]
                                      : lists[(g << 16) + m_base];
    __syncthreads();

    const int wave = t >> 6, lane = t & 63;
    const int wm = wave >> 1, wn = wave & 1;
    const int quad = lane >> 4, l16 = lane & 15;

    floatx4 acc[4][4];
    #pragma unroll
    for (int i = 0; i < 4; ++i)
        #pragma unroll
        for (int j = 0; j < 4; ++j) acc[i][j] = (floatx4)(0.0f);

    const float* wg = weight + (size_t)g * OUTF * MAXF;

    for (int k0 = 0; k0 < K; k0 += 32) {
        #pragma unroll
        for (int rep = 0; rep < 4; ++rep) {
            int id = t + rep * 256;
            int row = id >> 3;
            int kqq = id & 7;
            floatx4 av = *(const floatx4*)(x + (size_t)idxs[row] * MAXF + k0 + kqq * 4);
            unsigned long long pa = (unsigned long long)f2bf(av[0]) |
                ((unsigned long long)f2bf(av[1]) << 16) |
                ((unsigned long long)f2bf(av[2]) << 32) |
                ((unsigned long long)f2bf(av[3]) << 48);
            *(unsigned long long*)&As[row][kqq * 4] = pa;
            floatx4 bvv = *(const floatx4*)(wg + (size_t)(n_base + row) * MAXF + k0 + kqq * 4);
            unsigned long long pb = (unsigned long long)f2bf(bvv[0]) |
                ((unsigned long long)f2bf(bvv[1]) << 16) |
                ((unsigned long long)f2bf(bvv[2]) << 32) |
                ((unsigned long long)f2bf(bvv[3]) << 48);
            *(unsigned long long*)&Bs[row][kqq * 4] = pb;
        }
        __syncthreads();

        short8 af[4], bfr[4];
        #pragma unroll
        for (int mi = 0; mi < 4; ++mi)
            af[mi] = *(const short8*)&As[wm * 64 + mi * 16 + l16][quad * 8];
        #pragma unroll
        for (int ni = 0; ni < 4; ++ni)
            bfr[ni] = *(const short8*)&Bs[wn * 64 + ni * 16 + l16][quad * 8];
        #pragma unroll
        for (int mi = 0; mi < 4; ++mi)
            #pragma unroll
            for (int ni = 0; ni < 4; ++ni)
                acc[mi][ni] = __builtin_amdgcn_mfma_f32_16x16x32_bf16(
                    af[mi], bfr[ni], acc[mi][ni], 0, 0, 0);
        __syncthreads();
    }

    #pragma unroll
    for (int ni = 0; ni < 4; ++ni) {
        int col = n_base + wn * 64 + ni * 16 + l16;
        float bv = bias[g * OUTF + col];
        #pragma unroll
        for (int mi = 0; mi < 4; ++mi) {
            int mloc = wm * 64 + mi * 16 + quad * 4;
            #pragma unroll
            for (int r = 0; r < 4; ++r) {
                int m = mloc + r;
                if (m < rows)
                    out[(size_t)idxs[m] * OUTF + col] = acc[mi][ni][r] + bv;
            }
        }
    }
}

extern "C" void kernel_launch(void* const* d_in, const int* in_sizes, int n_in,
                              void* d_out, int out_size, void* d_ws, size_t ws_size,
                              hipStream_t stream) {
    const float* x      = (const float*)d_in[0];
    const int*   sizes  = (const int*)d_in[1];
    const float* weight = (const float*)d_in[2];
    const float* bias   = (const float*)d_in[3];
    float* out = (float*)d_out;

    char* ws = (char*)d_ws;
    int* cnt   = (int*)(ws + OFF_CNT);
    int* lists = (int*)(ws + OFF_LISTS);
    ushort_t* xb = (ushort_t*)(ws + OFF_XB);
    ushort_t* wb = (ushort_t*)(ws + OFF_WB);

    hipMemsetAsync(ws + OFF_CNT, 0, NGROUP * sizeof(int), stream);
    prep_kernel<<<N_TOKENS / 256, 256, 0, stream>>>(sizes, cnt, lists);

    if (ws_size >= WS_FULL) {
        conv_kernel<<<2048, 256, 0, stream>>>(x, weight, cnt, lists, xb, wb);
        // flat tile grid upper bound: 8 * (sum ceil(c_g/256)) <= 8 * 260 = 2080
        gemm_bf16_kernel<<<2080, 512, 0, stream>>>(xb, wb, bias, cnt, lists, out);
    } else {
        dim3 grid(OUTF / 128, N_TOKENS / 128, NGROUP);
        gemm_fp32_kernel<<<grid, 256, 0, stream>>>(x, weight, bias, cnt, lists, out);
    }
}